// Round 6
// baseline (135.495 us; speedup 1.0000x reference)
//
#include <hip/hip_runtime.h>

#define NBINS 15

// Wave-wide butterfly sum (64 lanes).
#define WAVE_RED(A)                                                             \
    do {                                                                        \
        A += __shfl_xor(A, 1, 64);  A += __shfl_xor(A, 2, 64);                  \
        A += __shfl_xor(A, 4, 64);  A += __shfl_xor(A, 8, 64);                  \
        A += __shfl_xor(A, 16, 64); A += __shfl_xor(A, 32, 64);                 \
    } while (0)

// Per-element update into a lane-private LDS slot via ds_add_f32 (fire-and-
// forget, no VALU round-trip, no address collisions between lanes).
// bin k covers (k/15,(k+1)/15] -> k = ceil(cv*15)-1 ; contribution d = cv - correct.
#define ECE_ELEM(cv_, pr_, lb_)                                                 \
    do {                                                                        \
        float cv = (cv_);                                                       \
        int b = (int)ceilf(cv * 15.0f) - 1;                                     \
        float d = cv - (((pr_) == (lb_)) ? 1.0f : 0.0f);                        \
        bool ok = ((unsigned)b < 15u); /* cv<=0 -> no bin */                    \
        d = ok ? d : 0.0f;                                                      \
        b = ok ? b : 0;                                                         \
        atomicAdd(&hist[wave][b][lane], d);                                     \
    } while (0)

__global__ __launch_bounds__(256) void ece_main(const float* __restrict__ conf,
                                                const int* __restrict__ pred,
                                                const int* __restrict__ lab,
                                                float* __restrict__ ws,
                                                int nvec) {
    // Lane-private histogram: bank = lane%32 for every bin -> conflict-free.
    __shared__ float hist[4][16][64];     // 16 KiB; 8 blocks/CU still fits 160 KiB
    __shared__ float s_blk[4][16];

    int wave = threadIdx.x >> 6;
    int lane = threadIdx.x & 63;

    {
        float* h = &hist[0][0][0];
        for (int j = threadIdx.x; j < 4 * 16 * 64; j += 256) h[j] = 0.0f;
    }
    __syncthreads();

    const float4* __restrict__ c4 = (const float4*)conf;
    const int4*   __restrict__ p4 = (const int4*)pred;
    const int4*   __restrict__ l4 = (const int4*)lab;

    int tid    = blockIdx.x * blockDim.x + threadIdx.x;
    int stride = gridDim.x * blockDim.x;

    int i = tid;
    // Unroll-by-2: 6 independent 16B loads in flight per iteration.
    for (; i + stride < nvec; i += 2 * stride) {
        float4 c0 = c4[i];
        float4 c1 = c4[i + stride];
        int4   p0 = p4[i];
        int4   p1 = p4[i + stride];
        int4   l0 = l4[i];
        int4   l1 = l4[i + stride];

        ECE_ELEM(c0.x, p0.x, l0.x); ECE_ELEM(c0.y, p0.y, l0.y);
        ECE_ELEM(c0.z, p0.z, l0.z); ECE_ELEM(c0.w, p0.w, l0.w);
        ECE_ELEM(c1.x, p1.x, l1.x); ECE_ELEM(c1.y, p1.y, l1.y);
        ECE_ELEM(c1.z, p1.z, l1.z); ECE_ELEM(c1.w, p1.w, l1.w);
    }
    for (; i < nvec; i += stride) {
        float4 c = c4[i];
        int4   p = p4[i];
        int4   l = l4[i];
        ECE_ELEM(c.x, p.x, l.x); ECE_ELEM(c.y, p.y, l.y);
        ECE_ELEM(c.z, p.z, l.z); ECE_ELEM(c.w, p.w, l.w);
    }

    // Per-wave reduce: fold 64 lane slots per bin (DS ops are in-order per
    // wave, so our own ds_adds are visible to our ds_reads without a barrier).
#pragma unroll
    for (int k = 0; k < NBINS; ++k) {
        float f = hist[wave][k][lane];
        WAVE_RED(f);
        if (lane == 0) s_blk[wave][k] = f;
    }
    __syncthreads();

    // Block partials: plain stores (slot is exclusively ours -> no init kernel,
    // no global atomics, no device fence; launch boundary publishes to ece_final).
    if (threadIdx.x < NBINS) {
        int k = threadIdx.x;
        ws[blockIdx.x * 16 + k] =
            s_blk[0][k] + s_blk[1][k] + s_blk[2][k] + s_blk[3][k];
    }
}

__global__ __launch_bounds__(256) void ece_final(const float* __restrict__ ws,
                                                 float* __restrict__ out,
                                                 float inv_n, int nblocks) {
    __shared__ float s_f[16];
    int t   = threadIdx.x;
    int bin = t >> 4;
    int idx = t & 15;
    float p = 0.0f;
    if (t < 240) {
        for (int j = idx; j < nblocks; j += 16) p += ws[j * 16 + bin];
    }
    // Reduce the 16 threads of each bin group (contained within one wave).
    p += __shfl_xor(p, 1, 64); p += __shfl_xor(p, 2, 64);
    p += __shfl_xor(p, 4, 64); p += __shfl_xor(p, 8, 64);
    if (t < 240 && idx == 0) s_f[bin] = p;
    __syncthreads();

    float v = 0.0f;
    if (t < NBINS) v = fabsf(s_f[t]) * inv_n;
    WAVE_RED(v);
    if (t == 0) out[0] = v;
}

extern "C" void kernel_launch(void* const* d_in, const int* in_sizes, int n_in,
                              void* d_out, int out_size, void* d_ws, size_t ws_size,
                              hipStream_t stream) {
    const float* conf = (const float*)d_in[0];
    const int*   pred = (const int*)d_in[1];
    const int*   lab  = (const int*)d_in[2];
    float* ws  = (float*)d_ws;
    float* out = (float*)d_out;
    int n    = in_sizes[0];
    int nvec = n / 4;        // N = 16777216, divisible by 4

    int nblocks = 2048;      // 8 blocks/CU on 256 CUs
    size_t need = (size_t)nblocks * 16 * sizeof(float);
    if (ws_size < need) {    // degrade gracefully if scratch is small
        nblocks = (int)(ws_size / (16 * sizeof(float)));
        if (nblocks < 1) nblocks = 1;
    }

    ece_main<<<nblocks, 256, 0, stream>>>(conf, pred, lab, ws, nvec);
    ece_final<<<1, 256, 0, stream>>>(ws, out, 1.0f / (float)n, nblocks);
}

// Round 7
// 63.464 us; speedup vs baseline: 2.1350x; 2.1350x over previous
//
#include <hip/hip_runtime.h>

#define NBINS 15
#define NBLK  2048   // 8 blocks/CU on 256 CUs

// Wave-wide butterfly sum (64 lanes).
#define WAVE_RED(A)                                                             \
    do {                                                                        \
        A += __shfl_xor(A, 1, 64);  A += __shfl_xor(A, 2, 64);                  \
        A += __shfl_xor(A, 4, 64);  A += __shfl_xor(A, 8, 64);                  \
        A += __shfl_xor(A, 16, 64); A += __shfl_xor(A, 32, 64);                 \
    } while (0)

// Per-element update on NAMED scalar accumulators (keeps everything in VGPRs).
// bin k covers (k/15,(k+1)/15] -> k = ceil(cv*15)-1 ; contribution d = cv - correct.
#define ECE_ELEM(cv_, pr_, lb_)                                                 \
    do {                                                                        \
        float cv = (cv_);                                                       \
        int b = (int)ceilf(cv * 15.0f) - 1;                                     \
        float d = cv - (((pr_) == (lb_)) ? 1.0f : 0.0f);                        \
        d = ((unsigned)b < 15u) ? d : 0.0f; /* cv<=0 -> no bin */               \
        a0  += (b == 0)  ? d : 0.0f;  a1  += (b == 1)  ? d : 0.0f;              \
        a2  += (b == 2)  ? d : 0.0f;  a3  += (b == 3)  ? d : 0.0f;              \
        a4  += (b == 4)  ? d : 0.0f;  a5  += (b == 5)  ? d : 0.0f;              \
        a6  += (b == 6)  ? d : 0.0f;  a7  += (b == 7)  ? d : 0.0f;              \
        a8  += (b == 8)  ? d : 0.0f;  a9  += (b == 9)  ? d : 0.0f;              \
        a10 += (b == 10) ? d : 0.0f;  a11 += (b == 11) ? d : 0.0f;              \
        a12 += (b == 12) ? d : 0.0f;  a13 += (b == 13) ? d : 0.0f;              \
        a14 += (b == 14) ? d : 0.0f;                                            \
    } while (0)

__global__ __launch_bounds__(256, 8) void ece_main(const float* __restrict__ conf,
                                                   const int* __restrict__ pred,
                                                   const int* __restrict__ lab,
                                                   float* __restrict__ ws,
                                                   int nvec) {
    float a0 = 0.0f, a1 = 0.0f, a2 = 0.0f, a3 = 0.0f, a4 = 0.0f;
    float a5 = 0.0f, a6 = 0.0f, a7 = 0.0f, a8 = 0.0f, a9 = 0.0f;
    float a10 = 0.0f, a11 = 0.0f, a12 = 0.0f, a13 = 0.0f, a14 = 0.0f;

    const float4* __restrict__ c4 = (const float4*)conf;
    const int4*   __restrict__ p4 = (const int4*)pred;
    const int4*   __restrict__ l4 = (const int4*)lab;

    const int tid    = blockIdx.x * blockDim.x + threadIdx.x;
    const int stride = gridDim.x * blockDim.x;
    const int niter  = nvec / stride;            // 4194304/524288 = 8 full iters

    // Software pipeline: loads for iteration it+1 are issued BEFORE the compute
    // of iteration it, so the ~400-cycle bin chain hides the global latency.
    int i = tid;
    float4 cc = c4[i];
    int4   pc = p4[i];
    int4   lc = l4[i];

    for (int it = 0; it < niter; ++it) {
        int inext = i + stride;
        int j = (it + 1 < niter) ? inext : tid;  // dummy (in-bounds) on last iter
        float4 cn = c4[j];
        int4   pn = p4[j];
        int4   ln = l4[j];

        ECE_ELEM(cc.x, pc.x, lc.x); ECE_ELEM(cc.y, pc.y, lc.y);
        ECE_ELEM(cc.z, pc.z, lc.z); ECE_ELEM(cc.w, pc.w, lc.w);

        cc = cn; pc = pn; lc = ln;
        i = inext;
    }
    // Remainder (none for N=16777216 with this grid; kept for safety).
    for (int r = tid + niter * stride; r < nvec; r += stride) {
        float4 c = c4[r];
        int4   p = p4[r];
        int4   l = l4[r];
        ECE_ELEM(c.x, p.x, l.x); ECE_ELEM(c.y, p.y, l.y);
        ECE_ELEM(c.z, p.z, l.z); ECE_ELEM(c.w, p.w, l.w);
    }

    // Wave-level butterfly reduction (64 lanes) per bin.
    WAVE_RED(a0);  WAVE_RED(a1);  WAVE_RED(a2);  WAVE_RED(a3);  WAVE_RED(a4);
    WAVE_RED(a5);  WAVE_RED(a6);  WAVE_RED(a7);  WAVE_RED(a8);  WAVE_RED(a9);
    WAVE_RED(a10); WAVE_RED(a11); WAVE_RED(a12); WAVE_RED(a13); WAVE_RED(a14);

    // Block partials via LDS; plain stores to a per-block slot (no init kernel,
    // no global atomics, no device fence — launch boundary publishes to final).
    __shared__ float s_h[4][16];
    int wave = threadIdx.x >> 6;
    int lane = threadIdx.x & 63;
    if (lane == 0) {
        s_h[wave][0]  = a0;  s_h[wave][1]  = a1;  s_h[wave][2]  = a2;
        s_h[wave][3]  = a3;  s_h[wave][4]  = a4;  s_h[wave][5]  = a5;
        s_h[wave][6]  = a6;  s_h[wave][7]  = a7;  s_h[wave][8]  = a8;
        s_h[wave][9]  = a9;  s_h[wave][10] = a10; s_h[wave][11] = a11;
        s_h[wave][12] = a12; s_h[wave][13] = a13; s_h[wave][14] = a14;
    }
    __syncthreads();
    if (threadIdx.x < NBINS) {
        int k = threadIdx.x;
        // Transposed layout ws[k*NBLK + block] -> final kernel reads coalesced.
        ws[k * NBLK + blockIdx.x] =
            s_h[0][k] + s_h[1][k] + s_h[2][k] + s_h[3][k];
    }
}

__global__ __launch_bounds__(256) void ece_final(const float* __restrict__ ws,
                                                 float* __restrict__ out,
                                                 float inv_n) {
    // 240 threads: 15 bins x 16 readers; each reads NBLK/16 = 128 contiguous-ish.
    __shared__ float s_f[16];
    int t   = threadIdx.x;
    int bin = t >> 4;
    int idx = t & 15;
    float p = 0.0f;
    if (t < 240) {
        const float* row = ws + bin * NBLK;
        for (int j = idx; j < NBLK; j += 16) p += row[j];
    }
    p += __shfl_xor(p, 1, 64); p += __shfl_xor(p, 2, 64);
    p += __shfl_xor(p, 4, 64); p += __shfl_xor(p, 8, 64);
    if (t < 240 && idx == 0) s_f[bin] = p;
    __syncthreads();

    float v = 0.0f;
    if (t < NBINS) v = fabsf(s_f[t]) * inv_n;
    WAVE_RED(v);
    if (t == 0) out[0] = v;
}

extern "C" void kernel_launch(void* const* d_in, const int* in_sizes, int n_in,
                              void* d_out, int out_size, void* d_ws, size_t ws_size,
                              hipStream_t stream) {
    const float* conf = (const float*)d_in[0];
    const int*   pred = (const int*)d_in[1];
    const int*   lab  = (const int*)d_in[2];
    float* ws  = (float*)d_ws;
    float* out = (float*)d_out;
    int n    = in_sizes[0];
    int nvec = n / 4;        // N = 16777216, divisible by 4

    ece_main<<<NBLK, 256, 0, stream>>>(conf, pred, lab, ws, nvec);
    ece_final<<<1, 256, 0, stream>>>(ws, out, 1.0f / (float)n);
}

// Round 8
// 46.154 us; speedup vs baseline: 2.9357x; 1.3750x over previous
//
#include <hip/hip_runtime.h>

#define NBINS 15
#define NREP 8            // global accumulator replicas (one per XCD)
#define REP_STRIDE 16
#define WS_WORDS (NREP * REP_STRIDE)

// ws layout: replica r at [r*16 .. r*16+14] = per-bin sum of (conf - correct)

__global__ void ece_init(float* __restrict__ ws) {
    int t = threadIdx.x;
    if (t < WS_WORDS) ws[t] = 0.0f;
}

// Per-element update on NAMED scalar accumulators (VGPR-resident).
// bin k covers (k/15,(k+1)/15] -> ceil(cv*15) == k+1 ; bounds implicit:
// cv<=0 -> ceil<=0 matches nothing; cv<1 -> ceil<=15 -> bin<=14.
// Contribution d = cv - (pred==lab).
#define ECE_ELEM(cv_, pr_, lb_)                                                 \
    do {                                                                        \
        float cv = (cv_);                                                       \
        int b1 = (int)ceilf(cv * 15.0f);                                        \
        float d = cv - (((pr_) == (lb_)) ? 1.0f : 0.0f);                        \
        a0  += (b1 == 1)  ? d : 0.0f;  a1  += (b1 == 2)  ? d : 0.0f;            \
        a2  += (b1 == 3)  ? d : 0.0f;  a3  += (b1 == 4)  ? d : 0.0f;            \
        a4  += (b1 == 5)  ? d : 0.0f;  a5  += (b1 == 6)  ? d : 0.0f;            \
        a6  += (b1 == 7)  ? d : 0.0f;  a7  += (b1 == 8)  ? d : 0.0f;            \
        a8  += (b1 == 9)  ? d : 0.0f;  a9  += (b1 == 10) ? d : 0.0f;            \
        a10 += (b1 == 11) ? d : 0.0f;  a11 += (b1 == 12) ? d : 0.0f;            \
        a12 += (b1 == 13) ? d : 0.0f;  a13 += (b1 == 14) ? d : 0.0f;            \
        a14 += (b1 == 15) ? d : 0.0f;                                           \
    } while (0)

#define WAVE_RED(A)                                                             \
    do {                                                                        \
        A += __shfl_xor(A, 1, 64);  A += __shfl_xor(A, 2, 64);                  \
        A += __shfl_xor(A, 4, 64);  A += __shfl_xor(A, 8, 64);                  \
        A += __shfl_xor(A, 16, 64); A += __shfl_xor(A, 32, 64);                 \
    } while (0)

__global__ __launch_bounds__(256, 8) void ece_main(const float* __restrict__ conf,
                                                   const int* __restrict__ pred,
                                                   const int* __restrict__ lab,
                                                   float* __restrict__ ws,
                                                   int nvec) {
    float a0 = 0.0f, a1 = 0.0f, a2 = 0.0f, a3 = 0.0f, a4 = 0.0f;
    float a5 = 0.0f, a6 = 0.0f, a7 = 0.0f, a8 = 0.0f, a9 = 0.0f;
    float a10 = 0.0f, a11 = 0.0f, a12 = 0.0f, a13 = 0.0f, a14 = 0.0f;

    const float4* __restrict__ c4 = (const float4*)conf;
    const int4*   __restrict__ p4 = (const int4*)pred;
    const int4*   __restrict__ l4 = (const int4*)lab;

    int tid    = blockIdx.x * blockDim.x + threadIdx.x;
    int stride = gridDim.x * blockDim.x;

    int i = tid;
    for (; i + stride < nvec; i += 2 * stride) {
        // Issue all 6 loads (96 B/lane) back-to-back...
        float4 c0 = c4[i];
        float4 c1 = c4[i + stride];
        int4   p0 = p4[i];
        int4   p1 = p4[i + stride];
        int4   l0 = l4[i];
        int4   l1 = l4[i + stride];
        // ...and forbid the scheduler from sinking them into the compute chain
        // (R7 showed the compiler otherwise reorders to 1 batch in flight).
        __builtin_amdgcn_sched_barrier(0);

        ECE_ELEM(c0.x, p0.x, l0.x); ECE_ELEM(c0.y, p0.y, l0.y);
        ECE_ELEM(c0.z, p0.z, l0.z); ECE_ELEM(c0.w, p0.w, l0.w);
        ECE_ELEM(c1.x, p1.x, l1.x); ECE_ELEM(c1.y, p1.y, l1.y);
        ECE_ELEM(c1.z, p1.z, l1.z); ECE_ELEM(c1.w, p1.w, l1.w);
    }
    for (; i < nvec; i += stride) {
        float4 c = c4[i];
        int4   p = p4[i];
        int4   l = l4[i];
        ECE_ELEM(c.x, p.x, l.x); ECE_ELEM(c.y, p.y, l.y);
        ECE_ELEM(c.z, p.z, l.z); ECE_ELEM(c.w, p.w, l.w);
    }

    // Wave-level butterfly reduction (64 lanes) per bin.
    WAVE_RED(a0);  WAVE_RED(a1);  WAVE_RED(a2);  WAVE_RED(a3);  WAVE_RED(a4);
    WAVE_RED(a5);  WAVE_RED(a6);  WAVE_RED(a7);  WAVE_RED(a8);  WAVE_RED(a9);
    WAVE_RED(a10); WAVE_RED(a11); WAVE_RED(a12); WAVE_RED(a13); WAVE_RED(a14);

    // Block-level reduction through LDS, one global atomic per bin per block.
    __shared__ float s_h[4][16];
    int wave = threadIdx.x >> 6;
    int lane = threadIdx.x & 63;
    if (lane == 0) {
        s_h[wave][0]  = a0;  s_h[wave][1]  = a1;  s_h[wave][2]  = a2;
        s_h[wave][3]  = a3;  s_h[wave][4]  = a4;  s_h[wave][5]  = a5;
        s_h[wave][6]  = a6;  s_h[wave][7]  = a7;  s_h[wave][8]  = a8;
        s_h[wave][9]  = a9;  s_h[wave][10] = a10; s_h[wave][11] = a11;
        s_h[wave][12] = a12; s_h[wave][13] = a13; s_h[wave][14] = a14;
    }
    __syncthreads();
    if (threadIdx.x < NBINS) {
        int k = threadIdx.x;
        float s = s_h[0][k] + s_h[1][k] + s_h[2][k] + s_h[3][k];
        atomicAdd(ws + (blockIdx.x & (NREP - 1)) * REP_STRIDE + k, s);
    }
    // No fused finalize / __threadfence: per-wave device fences cost ~330 us
    // on gfx950 (R2-R4). The launch boundary publishes ws to ece_final.
}

__global__ void ece_final(const float* __restrict__ ws, float* __restrict__ out,
                          float inv_n) {
    int k = threadIdx.x;
    float v = 0.0f;
    if (k < NBINS) {
        float s = 0.0f;
#pragma unroll
        for (int r = 0; r < NREP; ++r) s += ws[r * REP_STRIDE + k];
        v = fabsf(s) * inv_n;
    }
    WAVE_RED(v);
    if (k == 0) out[0] = v;
}

extern "C" void kernel_launch(void* const* d_in, const int* in_sizes, int n_in,
                              void* d_out, int out_size, void* d_ws, size_t ws_size,
                              hipStream_t stream) {
    const float* conf = (const float*)d_in[0];
    const int*   pred = (const int*)d_in[1];
    const int*   lab  = (const int*)d_in[2];
    float* ws  = (float*)d_ws;
    float* out = (float*)d_out;
    int n    = in_sizes[0];
    int nvec = n / 4;        // N = 16777216, divisible by 4

    ece_init<<<1, 128, 0, stream>>>(ws);
    ece_main<<<2048, 256, 0, stream>>>(conf, pred, lab, ws, nvec);
    ece_final<<<1, 64, 0, stream>>>(ws, out, 1.0f / (float)n);
}